// Round 8
// baseline (1998.552 us; speedup 1.0000x reference)
//
#include <hip/hip_runtime.h>
#include <hip/hip_bf16.h>

// ---------------------------------------------------------------------------
// CondGCN round 8:
//  - r7 counters: bucket3 = ~200us, WRITE_SIZE 244MB for a 16MB rows array
//    (= partial-line writeback per 4B scattered store, cross-XCD). Fine CSR
//    REMOVED. New: coarse 64-dst buckets; counting sort with per-(block,
//    bucket) contiguous runs (~80B, L2-combined); gather accumulates into a
//    64x64 LDS tile per bucket (ds_add_f32) and applies the pool dot there.
//  - transforms: 2 nodes per wave iteration (2x loads in flight) — they are
//    latency-bound on wave-uniform broadcast loads.
// ---------------------------------------------------------------------------

#define MAXNB 1600   // buckets of 64 dsts: ceil(100000/64)=1563 <= 1600

// out[n][64] = (relu?)(in[n][F] @ W^T + b); lane = output dim; 2 nodes/iter.
template <int F, bool RELU>
__global__ __launch_bounds__(256) void transform_kernel(
    const float* __restrict__ in, const float* __restrict__ W,
    const float* __restrict__ b, float* __restrict__ out, int n)
{
    const int lane  = threadIdx.x & 63;
    const int wid   = (int)((blockIdx.x * (unsigned)blockDim.x + threadIdx.x) >> 6);
    const int nwav  = (int)((gridDim.x * (unsigned)blockDim.x) >> 6);

    float w[F];
    const float4* wrow = reinterpret_cast<const float4*>(W + (size_t)lane * F);
#pragma unroll
    for (int k4 = 0; k4 < F / 4; ++k4) {
        float4 v = wrow[k4];
        w[4 * k4 + 0] = v.x; w[4 * k4 + 1] = v.y;
        w[4 * k4 + 2] = v.z; w[4 * k4 + 3] = v.w;
    }
    const float bias = b[lane];

    for (int i = wid; 2 * i < n; i += nwav) {
        const int n0 = 2 * i;
        const int n1 = n0 + 1;
        const bool has1 = n1 < n;
        const float4* x0 = reinterpret_cast<const float4*>(in + (size_t)n0 * F);
        const float4* x1 = reinterpret_cast<const float4*>(in + (size_t)(has1 ? n1 : n0) * F);
        float a0 = bias, a1 = 0.f;   // node n0, two chains
        float c0 = bias, c1 = 0.f;   // node n1, two chains
#pragma unroll
        for (int k4 = 0; k4 < F / 4; ++k4) {
            float4 v = x0[k4];
            float4 u = x1[k4];
            if (k4 & 1) {
                a1 += v.x * w[4 * k4 + 0]; a1 += v.y * w[4 * k4 + 1];
                a1 += v.z * w[4 * k4 + 2]; a1 += v.w * w[4 * k4 + 3];
                c1 += u.x * w[4 * k4 + 0]; c1 += u.y * w[4 * k4 + 1];
                c1 += u.z * w[4 * k4 + 2]; c1 += u.w * w[4 * k4 + 3];
            } else {
                a0 += v.x * w[4 * k4 + 0]; a0 += v.y * w[4 * k4 + 1];
                a0 += v.z * w[4 * k4 + 2]; a0 += v.w * w[4 * k4 + 3];
                c0 += u.x * w[4 * k4 + 0]; c0 += u.y * w[4 * k4 + 1];
                c0 += u.z * w[4 * k4 + 2]; c0 += u.w * w[4 * k4 + 3];
            }
        }
        float r0 = a0 + a1;
        if (RELU) r0 = fmaxf(r0, 0.0f);
        out[(size_t)n0 * 64 + lane] = r0;
        if (has1) {
            float r1 = c0 + c1;
            if (RELU) r1 = fmaxf(r1, 0.0f);
            out[(size_t)n1 * 64 + lane] = r1;
        }
    }
}

// concatenated-edge decode helper data passed as plain args (3 relations)

// K1: coarse bucket histogram (LDS-staged) over 3 concatenated dst lists
__global__ __launch_bounds__(256) void coarse_hist_kernel(
    const int* __restrict__ d0, int E0,
    const int* __restrict__ d1, int E1,
    const int* __restrict__ d2, int E2,
    int* __restrict__ btotal, int nb)
{
    __shared__ int lhist[MAXNB];
    for (int b = threadIdx.x; b < nb; b += 256) lhist[b] = 0;
    __syncthreads();
    const int total = E0 + E1 + E2;
    int i = blockIdx.x * blockDim.x + threadIdx.x;
    const int stride = gridDim.x * blockDim.x;
    for (; i < total; i += stride) {
        int t;
        if (i < E0)            t = d0[i];
        else if (i < E0 + E1)  t = d1[i - E0];
        else                   t = d2[i - E0 - E1];
        atomicAdd(&lhist[t >> 6], 1);
    }
    __syncthreads();
    for (int b = threadIdx.x; b < nb; b += 256) {
        int v = lhist[b];
        if (v) atomicAdd(&btotal[b], v);
    }
}

// K2: single-block exclusive scan of nb bucket totals -> bbase[nb+1], cursor
__global__ __launch_bounds__(1024) void coarse_scan_kernel(
    const int* __restrict__ btotal, int* __restrict__ bbase,
    int* __restrict__ bcursor, int nb)
{
    __shared__ int sh[1024];
    const int t = threadIdx.x;
    const int chunk = (nb + 1023) / 1024;
    const int beg = t * chunk;
    const int end = min(nb, beg + chunk);
    int s = 0;
    for (int i = beg; i < end; ++i) s += btotal[i];
    sh[t] = s;
    __syncthreads();
    for (int off = 1; off < 1024; off <<= 1) {
        int v = (t >= off) ? sh[t - off] : 0;
        __syncthreads();
        sh[t] += v;
        __syncthreads();
    }
    int run = (t == 0) ? 0 : sh[t - 1];
    for (int i = beg; i < end; ++i) {
        bbase[i] = run;
        bcursor[i] = run;
        run += btotal[i];
    }
    if (t == 1023) bbase[nb] = sh[1023];
}

// K3: per-block two-pass counting scatter into coarse buckets.
// Block histograms its chunk, claims ONE contiguous run per bucket, then
// writes packed (dst&63)<<18 | src_row entries into its run (L2-combined).
#define SCAT_BLOCKS 128
__global__ __launch_bounds__(512) void coarse_scatter_kernel(
    const int* __restrict__ s0, const int* __restrict__ d0, int E0, int base0,
    const int* __restrict__ s1, const int* __restrict__ d1, int E1, int base1,
    const int* __restrict__ s2, const int* __restrict__ d2, int E2, int base2,
    int* __restrict__ bcursor, int* __restrict__ pairs, int nb)
{
    __shared__ int lhist[MAXNB];
    __shared__ int lbase[MAXNB];
    const int total = E0 + E1 + E2;
    const int chunk = (total + SCAT_BLOCKS - 1) / SCAT_BLOCKS;
    const int beg = blockIdx.x * chunk;
    const int end = min(total, beg + chunk);

    for (int b = threadIdx.x; b < nb; b += 512) lhist[b] = 0;
    __syncthreads();

    // pass A: local histogram
    for (int i = beg + threadIdx.x; i < end; i += 512) {
        int t;
        if (i < E0)            t = d0[i];
        else if (i < E0 + E1)  t = d1[i - E0];
        else                   t = d2[i - E0 - E1];
        atomicAdd(&lhist[t >> 6], 1);
    }
    __syncthreads();

    // claims: one global atomic per (block,bucket); reset lhist -> cursor
    for (int b = threadIdx.x; b < nb; b += 512) {
        int cnt = lhist[b];
        lbase[b] = cnt ? atomicAdd(&bcursor[b], cnt) : 0;
        lhist[b] = 0;
    }
    __syncthreads();

    // pass B: scatter into this block's contiguous runs
    for (int i = beg + threadIdx.x; i < end; i += 512) {
        int t, v;
        if (i < E0)           { t = d0[i];           v = base0 + s0[i]; }
        else if (i < E0 + E1) { int k = i - E0;      t = d1[k]; v = base1 + s1[k]; }
        else                  { int k = i - E0 - E1; t = d2[k]; v = base2 + s2[k]; }
        const int b = t >> 6;
        const int r = atomicAdd(&lhist[b], 1);
        pairs[lbase[b] + r] = ((t & 63) << 18) | v;   // v < 151K < 2^18
    }
}

// K4: one block per bucket. 64x64 LDS accumulator (init = self-loop rows),
// stream the bucket's pair list with an 8-deep H-row load pipeline,
// ds_add_f32 accumulate, then pool dot (W_pool row in VGPRs) -> out_x.
__global__ __launch_bounds__(256) void gather_pool_coarse_kernel(
    const int* __restrict__ bbase, const int* __restrict__ pairs,
    const float* __restrict__ H, const float* __restrict__ agg_self,
    const float* __restrict__ W_pool, const float* __restrict__ b_pool,
    float* __restrict__ out_x, int n)
{
    __shared__ float accum[64][64];
    const int lane  = threadIdx.x & 63;
    const int wslot = threadIdx.x >> 6;
    const int b     = blockIdx.x;
    const int dst0  = b << 6;
    const int dlim  = min(64, n - dst0);
    const float* Hl = H + lane;

    float wp[64];
    const float4* wrow = reinterpret_cast<const float4*>(W_pool + (size_t)lane * 64);
#pragma unroll
    for (int k4 = 0; k4 < 16; ++k4) {
        float4 v = wrow[k4];
        wp[4 * k4 + 0] = v.x; wp[4 * k4 + 1] = v.y;
        wp[4 * k4 + 2] = v.z; wp[4 * k4 + 3] = v.w;
    }
    const float bias = b_pool[lane];

    // init accumulators with self-loop term
    for (int row = wslot; row < dlim; row += 4)
        accum[row][lane] = agg_self[(size_t)(dst0 + row) * 64 + lane];
    __syncthreads();

    const int beg = bbase[b];
    const int end = bbase[b + 1];
    for (int o = beg + wslot * 64; o < end; o += 4 * 64) {
        const int m = min(64, end - o);
        int pk = (lane < m) ? pairs[o + lane] : 0;
        int j = 0;
        for (; j + 8 <= m; j += 8) {
            int p0 = __shfl(pk, j + 0), p1 = __shfl(pk, j + 1);
            int p2 = __shfl(pk, j + 2), p3 = __shfl(pk, j + 3);
            int p4 = __shfl(pk, j + 4), p5 = __shfl(pk, j + 5);
            int p6 = __shfl(pk, j + 6), p7 = __shfl(pk, j + 7);
            float v0 = Hl[(size_t)(p0 & 0x3FFFF) * 64];
            float v1 = Hl[(size_t)(p1 & 0x3FFFF) * 64];
            float v2 = Hl[(size_t)(p2 & 0x3FFFF) * 64];
            float v3 = Hl[(size_t)(p3 & 0x3FFFF) * 64];
            float v4 = Hl[(size_t)(p4 & 0x3FFFF) * 64];
            float v5 = Hl[(size_t)(p5 & 0x3FFFF) * 64];
            float v6 = Hl[(size_t)(p6 & 0x3FFFF) * 64];
            float v7 = Hl[(size_t)(p7 & 0x3FFFF) * 64];
            unsafeAtomicAdd(&accum[p0 >> 18][lane], v0);
            unsafeAtomicAdd(&accum[p1 >> 18][lane], v1);
            unsafeAtomicAdd(&accum[p2 >> 18][lane], v2);
            unsafeAtomicAdd(&accum[p3 >> 18][lane], v3);
            unsafeAtomicAdd(&accum[p4 >> 18][lane], v4);
            unsafeAtomicAdd(&accum[p5 >> 18][lane], v5);
            unsafeAtomicAdd(&accum[p6 >> 18][lane], v6);
            unsafeAtomicAdd(&accum[p7 >> 18][lane], v7);
        }
        for (; j < m; ++j) {
            int p = __shfl(pk, j);
            unsafeAtomicAdd(&accum[p >> 18][lane], Hl[(size_t)(p & 0x3FFFF) * 64]);
        }
    }
    __syncthreads();

    // pool: out_x[row] = W_pool @ accum[row] + b_pool (no relu)
    for (int row = wslot; row < dlim; row += 4) {
        const float4* sr = reinterpret_cast<const float4*>(accum[row]);
        float p0 = bias, p1 = 0.f;
#pragma unroll
        for (int k4 = 0; k4 < 16; ++k4) {
            float4 v = sr[k4];
            if (k4 & 1) {
                p1 += v.x * wp[4 * k4 + 0]; p1 += v.y * wp[4 * k4 + 1];
                p1 += v.z * wp[4 * k4 + 2]; p1 += v.w * wp[4 * k4 + 3];
            } else {
                p0 += v.x * wp[4 * k4 + 0]; p0 += v.y * wp[4 * k4 + 1];
                p0 += v.z * wp[4 * k4 + 2]; p0 += v.w * wp[4 * k4 + 3];
            }
        }
        out_x[(size_t)(dst0 + row) * 64 + lane] = p0 + p1;
    }
}

extern "C" void kernel_launch(void* const* d_in, const int* in_sizes, int n_in,
                              void* d_out, int out_size, void* d_ws, size_t ws_size,
                              hipStream_t stream)
{
    const float* x = (const float*)d_in[0];
    const float* c = (const float*)d_in[1];
    const float* r = (const float*)d_in[2];
    const int* exx_s = (const int*)d_in[3];
    const int* exx_d = (const int*)d_in[4];
    const int* ecx_s = (const int*)d_in[5];
    const int* ecx_d = (const int*)d_in[6];
    const int* erx_s = (const int*)d_in[7];
    const int* erx_d = (const int*)d_in[8];
    const float* W_x  = (const float*)d_in[9];
    const float* b_x  = (const float*)d_in[10];
    const float* W_c  = (const float*)d_in[11];
    const float* b_c  = (const float*)d_in[12];
    const float* W_r  = (const float*)d_in[13];
    const float* b_r  = (const float*)d_in[14];
    const float* W_xx = (const float*)d_in[15];
    const float* b_xx = (const float*)d_in[16];
    const float* W_cx = (const float*)d_in[17];
    const float* b_cx = (const float*)d_in[18];
    const float* W_rx = (const float*)d_in[19];
    const float* b_rx = (const float*)d_in[20];
    const float* W_pool = (const float*)d_in[21];
    const float* b_pool = (const float*)d_in[22];

    const int N_x = in_sizes[0] / 64;
    const int N_c = in_sizes[1] / 32;
    const int N_r = in_sizes[2] / 48;
    const int E_xx = in_sizes[3];
    const int E_cx = in_sizes[5];
    const int E_rx = in_sizes[7];
    const int E_total = E_xx + E_cx + E_rx;
    const int NB = (N_x + 63) >> 6;        // 1563 <= MAXNB

    // workspace layout
    float* ws   = (float*)d_ws;
    float* agg  = ws;                                   // [N_x][64] self-loop term
    float* H    = agg + (size_t)N_x * 64;               // [(N_x+N_c+N_r)][64]
    float* h_xx = H;
    float* h_cx = H + (size_t)N_x * 64;
    float* h_rx = H + (size_t)(N_x + N_c) * 64;
    int* btotal  = (int*)(H + (size_t)(N_x + N_c + N_r) * 64);   // [NB]
    int* bbase   = btotal + NB;                          // [NB+1]
    int* bcursor = bbase + NB + 1;                       // [NB]
    int* pairs   = bcursor + NB;                         // [E_total]

    float* out_x = (float*)d_out;                       // [N_x][64]
    float* out_c = out_x + (size_t)N_x * 64;            // [N_c][64]
    float* out_r = out_c + (size_t)N_c * 64;            // [N_r][64]

    const int BLK = 256;
    const int TGRID = 1024;

    // per-node transforms (2 nodes per wave iteration)
    transform_kernel<64, true><<<TGRID, BLK, 0, stream>>>(x, W_x,  b_x,  agg,  N_x);
    transform_kernel<64, true><<<TGRID, BLK, 0, stream>>>(x, W_xx, b_xx, h_xx, N_x);
    transform_kernel<32, true><<<TGRID, BLK, 0, stream>>>(c, W_cx, b_cx, h_cx, N_c);
    transform_kernel<48, true><<<TGRID, BLK, 0, stream>>>(r, W_rx, b_rx, h_rx, N_r);
    transform_kernel<32, true><<<TGRID, BLK, 0, stream>>>(c, W_c,  b_c,  out_c, N_c);
    transform_kernel<48, true><<<TGRID, BLK, 0, stream>>>(r, W_r,  b_r,  out_r, N_r);

    // coarse bucket sort of edges (no fine CSR)
    hipMemsetAsync(btotal, 0, (size_t)NB * sizeof(int), stream);
    coarse_hist_kernel<<<256, BLK, 0, stream>>>(exx_d, E_xx, ecx_d, E_cx, erx_d, E_rx,
                                                btotal, NB);
    coarse_scan_kernel<<<1, 1024, 0, stream>>>(btotal, bbase, bcursor, NB);
    coarse_scatter_kernel<<<SCAT_BLOCKS, 512, 0, stream>>>(
        exx_s, exx_d, E_xx, 0,
        ecx_s, ecx_d, E_cx, N_x,
        erx_s, erx_d, E_rx, N_x + N_c,
        bcursor, pairs, NB);

    // gather + pool per bucket (LDS accumulate, writes out_x directly)
    gather_pool_coarse_kernel<<<NB, BLK, 0, stream>>>(bbase, pairs, H, agg,
                                                      W_pool, b_pool, out_x, N_x);
}

// Round 9
// 619.159 us; speedup vs baseline: 3.2278x; 3.2278x over previous
//
#include <hip/hip_runtime.h>
#include <hip/hip_bf16.h>

// ---------------------------------------------------------------------------
// CondGCN round 9:
//  - r8 post-mortem: gather with LDS ds_atomic accumulate = 1555us (VALU 3.8%,
//    HBM 3% -> 192M serialized LDS atomics). REVERTED to r7's register
//    gather_pool (wave-per-node, 8-deep load pipeline) which was <190us.
//  - r7's bucket3 write-amplification (244MB for 16MB of 4B scattered stores)
//    fixed by TWO-LEVEL sort: r8's coarse 64-dst-bucket counting sort
//    (contiguous per-(block,bucket) runs, L2-combined) + NEW per-bucket
//    fine sort (64-counter LDS histogram; random writes confined to the
//    bucket's ~8KB region on one XCD -> ~1x write amplification).
// ---------------------------------------------------------------------------

#define MAXNB 1600   // buckets of 64 dsts: ceil(100000/64)=1563 <= 1600

// out[n][64] = (relu?)(in[n][F] @ W^T + b); lane = output dim; 2 nodes/iter.
template <int F, bool RELU>
__global__ __launch_bounds__(256) void transform_kernel(
    const float* __restrict__ in, const float* __restrict__ W,
    const float* __restrict__ b, float* __restrict__ out, int n)
{
    const int lane  = threadIdx.x & 63;
    const int wid   = (int)((blockIdx.x * (unsigned)blockDim.x + threadIdx.x) >> 6);
    const int nwav  = (int)((gridDim.x * (unsigned)blockDim.x) >> 6);

    float w[F];
    const float4* wrow = reinterpret_cast<const float4*>(W + (size_t)lane * F);
#pragma unroll
    for (int k4 = 0; k4 < F / 4; ++k4) {
        float4 v = wrow[k4];
        w[4 * k4 + 0] = v.x; w[4 * k4 + 1] = v.y;
        w[4 * k4 + 2] = v.z; w[4 * k4 + 3] = v.w;
    }
    const float bias = b[lane];

    for (int i = wid; 2 * i < n; i += nwav) {
        const int n0 = 2 * i;
        const int n1 = n0 + 1;
        const bool has1 = n1 < n;
        const float4* x0 = reinterpret_cast<const float4*>(in + (size_t)n0 * F);
        const float4* x1 = reinterpret_cast<const float4*>(in + (size_t)(has1 ? n1 : n0) * F);
        float a0 = bias, a1 = 0.f;
        float c0 = bias, c1 = 0.f;
#pragma unroll
        for (int k4 = 0; k4 < F / 4; ++k4) {
            float4 v = x0[k4];
            float4 u = x1[k4];
            if (k4 & 1) {
                a1 += v.x * w[4 * k4 + 0]; a1 += v.y * w[4 * k4 + 1];
                a1 += v.z * w[4 * k4 + 2]; a1 += v.w * w[4 * k4 + 3];
                c1 += u.x * w[4 * k4 + 0]; c1 += u.y * w[4 * k4 + 1];
                c1 += u.z * w[4 * k4 + 2]; c1 += u.w * w[4 * k4 + 3];
            } else {
                a0 += v.x * w[4 * k4 + 0]; a0 += v.y * w[4 * k4 + 1];
                a0 += v.z * w[4 * k4 + 2]; a0 += v.w * w[4 * k4 + 3];
                c0 += u.x * w[4 * k4 + 0]; c0 += u.y * w[4 * k4 + 1];
                c0 += u.z * w[4 * k4 + 2]; c0 += u.w * w[4 * k4 + 3];
            }
        }
        float r0 = a0 + a1;
        if (RELU) r0 = fmaxf(r0, 0.0f);
        out[(size_t)n0 * 64 + lane] = r0;
        if (has1) {
            float r1 = c0 + c1;
            if (RELU) r1 = fmaxf(r1, 0.0f);
            out[(size_t)n1 * 64 + lane] = r1;
        }
    }
}

// K1: coarse bucket histogram (LDS-staged) over 3 concatenated dst lists
__global__ __launch_bounds__(256) void coarse_hist_kernel(
    const int* __restrict__ d0, int E0,
    const int* __restrict__ d1, int E1,
    const int* __restrict__ d2, int E2,
    int* __restrict__ btotal, int nb)
{
    __shared__ int lhist[MAXNB];
    for (int b = threadIdx.x; b < nb; b += 256) lhist[b] = 0;
    __syncthreads();
    const int total = E0 + E1 + E2;
    int i = blockIdx.x * blockDim.x + threadIdx.x;
    const int stride = gridDim.x * blockDim.x;
    for (; i < total; i += stride) {
        int t;
        if (i < E0)            t = d0[i];
        else if (i < E0 + E1)  t = d1[i - E0];
        else                   t = d2[i - E0 - E1];
        atomicAdd(&lhist[t >> 6], 1);
    }
    __syncthreads();
    for (int b = threadIdx.x; b < nb; b += 256) {
        int v = lhist[b];
        if (v) atomicAdd(&btotal[b], v);
    }
}

// K2: single-block exclusive scan of nb bucket totals -> bbase[nb+1], cursor
__global__ __launch_bounds__(1024) void coarse_scan_kernel(
    const int* __restrict__ btotal, int* __restrict__ bbase,
    int* __restrict__ bcursor, int nb)
{
    __shared__ int sh[1024];
    const int t = threadIdx.x;
    const int chunk = (nb + 1023) / 1024;
    const int beg = t * chunk;
    const int end = min(nb, beg + chunk);
    int s = 0;
    for (int i = beg; i < end; ++i) s += btotal[i];
    sh[t] = s;
    __syncthreads();
    for (int off = 1; off < 1024; off <<= 1) {
        int v = (t >= off) ? sh[t - off] : 0;
        __syncthreads();
        sh[t] += v;
        __syncthreads();
    }
    int run = (t == 0) ? 0 : sh[t - 1];
    for (int i = beg; i < end; ++i) {
        bbase[i] = run;
        bcursor[i] = run;
        run += btotal[i];
    }
    if (t == 1023) bbase[nb] = sh[1023];
}

// K3: per-block two-pass counting scatter into coarse buckets.
// Packed entry: (dst&63)<<18 | global_src_row   (src_row < 151K < 2^18)
#define SCAT_BLOCKS 128
__global__ __launch_bounds__(512) void coarse_scatter_kernel(
    const int* __restrict__ s0, const int* __restrict__ d0, int E0, int base0,
    const int* __restrict__ s1, const int* __restrict__ d1, int E1, int base1,
    const int* __restrict__ s2, const int* __restrict__ d2, int E2, int base2,
    int* __restrict__ bcursor, int* __restrict__ pairs, int nb)
{
    __shared__ int lhist[MAXNB];
    __shared__ int lbase[MAXNB];
    const int total = E0 + E1 + E2;
    const int chunk = (total + SCAT_BLOCKS - 1) / SCAT_BLOCKS;
    const int beg = blockIdx.x * chunk;
    const int end = min(total, beg + chunk);

    for (int b = threadIdx.x; b < nb; b += 512) lhist[b] = 0;
    __syncthreads();

    for (int i = beg + threadIdx.x; i < end; i += 512) {
        int t;
        if (i < E0)            t = d0[i];
        else if (i < E0 + E1)  t = d1[i - E0];
        else                   t = d2[i - E0 - E1];
        atomicAdd(&lhist[t >> 6], 1);
    }
    __syncthreads();

    for (int b = threadIdx.x; b < nb; b += 512) {
        int cnt = lhist[b];
        lbase[b] = cnt ? atomicAdd(&bcursor[b], cnt) : 0;
        lhist[b] = 0;
    }
    __syncthreads();

    for (int i = beg + threadIdx.x; i < end; i += 512) {
        int t, v;
        if (i < E0)           { t = d0[i];           v = base0 + s0[i]; }
        else if (i < E0 + E1) { int k = i - E0;      t = d1[k]; v = base1 + s1[k]; }
        else                  { int k = i - E0 - E1; t = d2[k]; v = base2 + s2[k]; }
        const int b = t >> 6;
        const int r = atomicAdd(&lhist[b], 1);
        pairs[lbase[b] + r] = ((t & 63) << 18) | v;
    }
}

// K3b: fine sort within each bucket. One block per bucket; 64-counter LDS
// histogram + scan; scatter src rows into the bucket's CONTIGUOUS region of
// `rows` (random only within ~8KB on one XCD -> L2 write-combined).
// Also emits the fine CSR offsets.
__global__ __launch_bounds__(256) void finesort_kernel(
    const int* __restrict__ bbase, const int* __restrict__ pairs,
    int* __restrict__ rows, int* __restrict__ offsets, int n, int nb)
{
    __shared__ int cnt[64];
    __shared__ int off[64];
    const int b    = blockIdx.x;
    const int beg  = bbase[b];
    const int end  = bbase[b + 1];
    const int dst0 = b << 6;
    const int dlim = min(64, n - dst0);

    if (threadIdx.x < 64) cnt[threadIdx.x] = 0;
    __syncthreads();

    for (int i = beg + threadIdx.x; i < end; i += 256)
        atomicAdd(&cnt[pairs[i] >> 18], 1);
    __syncthreads();

    if (threadIdx.x == 0) {
        int run = beg;
        for (int d = 0; d < 64; ++d) {
            off[d] = run;
            run += cnt[d];
            cnt[d] = 0;               // becomes cursor
        }
    }
    __syncthreads();

    if (threadIdx.x < dlim) offsets[dst0 + threadIdx.x] = off[threadIdx.x];
    if (b == nb - 1 && threadIdx.x == 0) offsets[n] = end;

    for (int i = beg + threadIdx.x; i < end; i += 256) {
        const int p = pairs[i];
        const int d = p >> 18;
        const int pos = off[d] + atomicAdd(&cnt[d], 1);
        rows[pos] = p & 0x3FFFF;
    }
}

// K4 (r7's proven version): fused gather + pool.
//   row = agg_self[node] + sum_{in-edges} H[row_id]   (registers, lane=dim)
//   out_x[node] = W_pool @ row + b_pool               (per-wave LDS exchange)
__global__ __launch_bounds__(256) void gather_pool_kernel(
    const int* __restrict__ offsets, const int* __restrict__ rows,
    const float* __restrict__ H, const float* __restrict__ agg_self,
    const float* __restrict__ W_pool, const float* __restrict__ b_pool,
    float* __restrict__ out_x, int n)
{
    __shared__ float srow[4][64];
    const int lane  = threadIdx.x & 63;
    const int wslot = threadIdx.x >> 6;
    const int wid   = (int)((blockIdx.x * (unsigned)blockDim.x + threadIdx.x) >> 6);
    const int nwav  = (int)((gridDim.x * (unsigned)blockDim.x) >> 6);
    const float* Hl = H + lane;

    float wp[64];
    const float4* wrow = reinterpret_cast<const float4*>(W_pool + (size_t)lane * 64);
#pragma unroll
    for (int k4 = 0; k4 < 16; ++k4) {
        float4 v = wrow[k4];
        wp[4 * k4 + 0] = v.x; wp[4 * k4 + 1] = v.y;
        wp[4 * k4 + 2] = v.z; wp[4 * k4 + 3] = v.w;
    }
    const float bias = b_pool[lane];

    for (int node = wid; node < n; node += nwav) {
        const int beg = offsets[node];
        const int end = offsets[node + 1];
        float acc0 = agg_self[(size_t)node * 64 + lane];
        float acc1 = 0.f, acc2 = 0.f, acc3 = 0.f;
        int o = beg;
        while (o < end) {
            const int m = min(64, end - o);
            int idx = (lane < m) ? rows[o + lane] : 0;
            int j = 0;
            for (; j + 8 <= m; j += 8) {
                int r0 = __shfl(idx, j + 0), r1 = __shfl(idx, j + 1);
                int r2 = __shfl(idx, j + 2), r3 = __shfl(idx, j + 3);
                int r4 = __shfl(idx, j + 4), r5 = __shfl(idx, j + 5);
                int r6 = __shfl(idx, j + 6), r7 = __shfl(idx, j + 7);
                float v0 = Hl[(size_t)r0 * 64];
                float v1 = Hl[(size_t)r1 * 64];
                float v2 = Hl[(size_t)r2 * 64];
                float v3 = Hl[(size_t)r3 * 64];
                float v4 = Hl[(size_t)r4 * 64];
                float v5 = Hl[(size_t)r5 * 64];
                float v6 = Hl[(size_t)r6 * 64];
                float v7 = Hl[(size_t)r7 * 64];
                acc0 += v0; acc1 += v1; acc2 += v2; acc3 += v3;
                acc0 += v4; acc1 += v5; acc2 += v6; acc3 += v7;
            }
            for (; j < m; ++j)
                acc0 += Hl[(size_t)__shfl(idx, j) * 64];
            o += m;
        }
        const float rowv = (acc0 + acc1) + (acc2 + acc3);

        srow[wslot][lane] = rowv;
        asm volatile("s_waitcnt lgkmcnt(0)" ::: "memory");
        __builtin_amdgcn_sched_barrier(0);
        const float4* sr = reinterpret_cast<const float4*>(srow[wslot]);
        float p0 = bias, p1 = 0.f;
#pragma unroll
        for (int k4 = 0; k4 < 16; ++k4) {
            float4 v = sr[k4];
            if (k4 & 1) {
                p1 += v.x * wp[4 * k4 + 0]; p1 += v.y * wp[4 * k4 + 1];
                p1 += v.z * wp[4 * k4 + 2]; p1 += v.w * wp[4 * k4 + 3];
            } else {
                p0 += v.x * wp[4 * k4 + 0]; p0 += v.y * wp[4 * k4 + 1];
                p0 += v.z * wp[4 * k4 + 2]; p0 += v.w * wp[4 * k4 + 3];
            }
        }
        out_x[(size_t)node * 64 + lane] = p0 + p1;
    }
}

extern "C" void kernel_launch(void* const* d_in, const int* in_sizes, int n_in,
                              void* d_out, int out_size, void* d_ws, size_t ws_size,
                              hipStream_t stream)
{
    const float* x = (const float*)d_in[0];
    const float* c = (const float*)d_in[1];
    const float* r = (const float*)d_in[2];
    const int* exx_s = (const int*)d_in[3];
    const int* exx_d = (const int*)d_in[4];
    const int* ecx_s = (const int*)d_in[5];
    const int* ecx_d = (const int*)d_in[6];
    const int* erx_s = (const int*)d_in[7];
    const int* erx_d = (const int*)d_in[8];
    const float* W_x  = (const float*)d_in[9];
    const float* b_x  = (const float*)d_in[10];
    const float* W_c  = (const float*)d_in[11];
    const float* b_c  = (const float*)d_in[12];
    const float* W_r  = (const float*)d_in[13];
    const float* b_r  = (const float*)d_in[14];
    const float* W_xx = (const float*)d_in[15];
    const float* b_xx = (const float*)d_in[16];
    const float* W_cx = (const float*)d_in[17];
    const float* b_cx = (const float*)d_in[18];
    const float* W_rx = (const float*)d_in[19];
    const float* b_rx = (const float*)d_in[20];
    const float* W_pool = (const float*)d_in[21];
    const float* b_pool = (const float*)d_in[22];

    const int N_x = in_sizes[0] / 64;
    const int N_c = in_sizes[1] / 32;
    const int N_r = in_sizes[2] / 48;
    const int E_xx = in_sizes[3];
    const int E_cx = in_sizes[5];
    const int E_rx = in_sizes[7];
    const int E_total = E_xx + E_cx + E_rx;
    const int NB = (N_x + 63) >> 6;        // 1563 <= MAXNB

    // workspace layout
    float* ws   = (float*)d_ws;
    float* agg  = ws;                                   // [N_x][64] self-loop
    float* H    = agg + (size_t)N_x * 64;               // [(N_x+N_c+N_r)][64]
    float* h_xx = H;
    float* h_cx = H + (size_t)N_x * 64;
    float* h_rx = H + (size_t)(N_x + N_c) * 64;
    int* btotal  = (int*)(H + (size_t)(N_x + N_c + N_r) * 64);   // [NB]
    int* bbase   = btotal + NB;                          // [NB+1]
    int* bcursor = bbase + NB + 1;                       // [NB]
    int* pairs   = bcursor + NB;                         // [E_total]
    int* rows    = pairs + E_total;                      // [E_total]
    int* offsets = rows + E_total;                       // [N_x+1]

    float* out_x = (float*)d_out;                       // [N_x][64]
    float* out_c = out_x + (size_t)N_x * 64;            // [N_c][64]
    float* out_r = out_c + (size_t)N_c * 64;            // [N_r][64]

    const int BLK = 256;
    const int TGRID = 1024;

    // per-node transforms (2 nodes per wave iteration)
    transform_kernel<64, true><<<TGRID, BLK, 0, stream>>>(x, W_x,  b_x,  agg,  N_x);
    transform_kernel<64, true><<<TGRID, BLK, 0, stream>>>(x, W_xx, b_xx, h_xx, N_x);
    transform_kernel<32, true><<<TGRID, BLK, 0, stream>>>(c, W_cx, b_cx, h_cx, N_c);
    transform_kernel<48, true><<<TGRID, BLK, 0, stream>>>(r, W_rx, b_rx, h_rx, N_r);
    transform_kernel<32, true><<<TGRID, BLK, 0, stream>>>(c, W_c,  b_c,  out_c, N_c);
    transform_kernel<48, true><<<TGRID, BLK, 0, stream>>>(r, W_r,  b_r,  out_r, N_r);

    // two-level dst sort: coarse 64-buckets, then fine within bucket
    hipMemsetAsync(btotal, 0, (size_t)NB * sizeof(int), stream);
    coarse_hist_kernel<<<256, BLK, 0, stream>>>(exx_d, E_xx, ecx_d, E_cx, erx_d, E_rx,
                                                btotal, NB);
    coarse_scan_kernel<<<1, 1024, 0, stream>>>(btotal, bbase, bcursor, NB);
    coarse_scatter_kernel<<<SCAT_BLOCKS, 512, 0, stream>>>(
        exx_s, exx_d, E_xx, 0,
        ecx_s, ecx_d, E_cx, N_x,
        erx_s, erx_d, E_rx, N_x + N_c,
        bcursor, pairs, NB);
    finesort_kernel<<<NB, BLK, 0, stream>>>(bbase, pairs, rows, offsets, N_x, NB);

    // fused gather + pool (register accumulate, writes out_x directly)
    gather_pool_kernel<<<2048, BLK, 0, stream>>>(offsets, rows, H, agg,
                                                 W_pool, b_pool, out_x, N_x);
}